// Round 6
// baseline (271.916 us; speedup 1.0000x reference)
//
#include <hip/hip_runtime.h>
#include <hip/hip_bf16.h>
#include <stdint.h>

typedef __hip_bfloat16 bf16;
typedef __attribute__((ext_vector_type(8))) short s16x8;   // 8 bf16 (MFMA A/B frag)
typedef __attribute__((ext_vector_type(4))) short s16x4;   // 4 bf16
typedef __attribute__((ext_vector_type(4))) float f32x4;   // MFMA C/D frag

__device__ __forceinline__ short f2bf_bits(float f) {
    union { bf16 b; short s; } u; u.b = __float2bfloat16(f); return u.s;
}

__device__ __forceinline__ void gload_lds16(const void* g, void* l) {
    __builtin_amdgcn_global_load_lds(
        (const __attribute__((address_space(1))) void*)(uintptr_t)g,
        (__attribute__((address_space(3))) void*)(uintptr_t)l,
        16, 0, 0);
}

__device__ __forceinline__ f32x4 mfma16(s16x8 a, s16x8 b, f32x4 c) {
    return __builtin_amdgcn_mfma_f32_16x16x32_bf16(a, b, c, 0, 0, 0);
}

// ---------------- prep: both weight transposes (fp32 -> bf16, out[C][R]=in[R][C]) + tail ----------------
__global__ __launch_bounds__(256) void prep_kernel(const float* __restrict__ Wq,
                                                   const float* __restrict__ Wp,
                                                   bf16* __restrict__ Wqt,
                                                   bf16* __restrict__ Wpt,
                                                   const int* __restrict__ sz,
                                                   float* __restrict__ tailout) {
    if (blockIdx.x == 0 && blockIdx.y == 0 && threadIdx.x == 0)
        tailout[0] = (float)sz[0];
    __shared__ float t[32][33];
    const float* in; bf16* out; int C, c0;
    if (blockIdx.x < 48) { in = Wq; out = Wqt; C = 1536; c0 = blockIdx.x * 32; }
    else                 { in = Wp; out = Wpt; C = 512;  c0 = (blockIdx.x - 48) * 32; }
    int r0 = blockIdx.y * 32;
    int lx = threadIdx.x & 31, ly = threadIdx.x >> 5;
    for (int i = ly; i < 32; i += 8)
        t[i][lx] = in[(size_t)(r0 + i) * C + (c0 + lx)];
    __syncthreads();
    for (int i = ly; i < 32; i += 8)
        out[(size_t)(c0 + i) * 512 + (r0 + lx)] = __float2bfloat16(t[lx][i]);
}

// ---------------- GEMM1: qkv = bf16(x) @ Wqkv_t^T + b; fused fp32->bf16 A-staging ----------------
// x [32768][512] fp32 reg-staged -> swizzled ds_write; Bt [1536][512] bf16 via global_load_lds.
// Tile 128x128, BK=64, 4 waves. T1 XCD swizzle (nwg=3072 %8==0).
__global__ __launch_bounds__(256, 2) void gemm_qkv_kernel(
    const float* __restrict__ X, const bf16* __restrict__ Bt,
    const float* __restrict__ bias,
    bf16* __restrict__ qT, bf16* __restrict__ kT, bf16* __restrict__ V) {
    __shared__ __align__(16) char smem[33280];           // max(As+Bs=32KB, tr=128*130*2)
    bf16* As = (bf16*)smem;                              // [128][64] swizzled
    bf16* Bs = (bf16*)(smem + 16384);
    const int tid = threadIdx.x;
    const int wid = tid >> 6, lane = tid & 63;
    const int r16 = lane & 15, rg = lane >> 4;
    const int wr = wid >> 1, wc = wid & 1;
    const int flat = blockIdx.y * 12 + blockIdx.x;       // 3072 tiles
    const int nb = (flat & 7) * 384 + (flat >> 3);
    const int n0 = (nb % 12) * 128;
    const int m0 = (nb / 12) * 128;

    f32x4 acc[4][4] = {};
    for (int ks = 0; ks < 8; ++ks) {
        const int k0 = ks * 64;
        // B: async global->LDS (in flight while A converts)
#pragma unroll
        for (int it = 0; it < 4; ++it) {
            int f = (it * 256 + tid) << 4;
            int row = f >> 7;
            int sc = ((f >> 4) & 7) ^ (row & 7);
            gload_lds16((const char*)(Bt + (size_t)(n0 + row) * 512 + k0) + (sc << 4),
                        (char*)Bs + ((it * 256 + (wid << 6)) << 4));
        }
        // A: fp32 load -> bf16 convert -> swizzled ds_write_b128
#pragma unroll
        for (int it = 0; it < 4; ++it) {
            int cidx = it * 256 + tid;                   // 16B-chunk index in A tile
            int row = cidx >> 3, c8 = cidx & 7;
            const float* src = X + (size_t)(m0 + row) * 512 + k0 + (c8 << 3);
            f32x4 a = *(const f32x4*)src;
            f32x4 b = *(const f32x4*)(src + 4);
            s16x8 o;
            o[0] = f2bf_bits(a[0]); o[1] = f2bf_bits(a[1]);
            o[2] = f2bf_bits(a[2]); o[3] = f2bf_bits(a[3]);
            o[4] = f2bf_bits(b[0]); o[5] = f2bf_bits(b[1]);
            o[6] = f2bf_bits(b[2]); o[7] = f2bf_bits(b[3]);
            *(s16x8*)((char*)As + (row << 7) + ((c8 ^ (row & 7)) << 4)) = o;
        }
        __syncthreads();
#pragma unroll
        for (int kk = 0; kk < 2; ++kk) {
            s16x8 af[4], bfv[4];
#pragma unroll
            for (int mi = 0; mi < 4; ++mi) {
                int row = (wr << 6) + (mi << 4) + r16;
                int off = (row << 7) + ((((kk << 2) + rg) ^ (row & 7)) << 4);
                af[mi] = *(const s16x8*)((const char*)As + off);
            }
#pragma unroll
            for (int ni = 0; ni < 4; ++ni) {
                int row = (wc << 6) + (ni << 4) + r16;
                int off = (row << 7) + ((((kk << 2) + rg) ^ (row & 7)) << 4);
                bfv[ni] = *(const s16x8*)((const char*)Bs + off);
            }
#pragma unroll
            for (int mi = 0; mi < 4; ++mi)
#pragma unroll
                for (int ni = 0; ni < 4; ++ni)
                    acc[mi][ni] = mfma16(af[mi], bfv[ni], acc[mi][ni]);
        }
        __syncthreads();
    }

    // epilogue: bias, (q) scale, route through LDS [128][130] for layout
    const int bb = m0 >> 12;        // batch
    const int l0 = m0 & 4095;       // l within batch
    const float scale = (n0 < 512) ? 0.015625f : 1.0f;   // L^-0.5 = 1/64 on q
    bf16* tr = (bf16*)smem;
    float bv[4];
#pragma unroll
    for (int ni = 0; ni < 4; ++ni)
        bv[ni] = bias[n0 + (wc << 6) + (ni << 4) + r16];
#pragma unroll
    for (int mi = 0; mi < 4; ++mi)
#pragma unroll
        for (int ni = 0; ni < 4; ++ni) {
            int col = (wc << 6) + (ni << 4) + r16;
#pragma unroll
            for (int r = 0; r < 4; ++r) {
                int row = (wr << 6) + (mi << 4) + (rg << 2) + r;
                tr[row * 130 + col] = __float2bfloat16((acc[mi][ni][r] + bv[ni]) * scale);
            }
        }
    __syncthreads();
    if (n0 < 1024) {                 // q or k block: transposed write qT[b][c][l]
        bf16* dst; int c0;
        if (n0 < 512) { dst = qT; c0 = n0; } else { dst = kT; c0 = n0 - 512; }
#pragma unroll 4
        for (int it = 0; it < 64; ++it) {
            int flat2 = it * 256 + tid;
            int cl = flat2 >> 7, ll = flat2 & 127;
            dst[((size_t)(bb * 512 + c0 + cl) << 12) + (l0 + ll)] = tr[ll * 130 + cl];
        }
    } else {                          // v block: normal layout V[m][c]
        int c0 = n0 - 1024;
#pragma unroll 4
        for (int it = 0; it < 64; ++it) {
            int flat2 = it * 256 + tid;
            int rr = flat2 >> 7, cc = flat2 & 127;
            V[((size_t)(m0 + rr) << 9) + (c0 + cc)] = tr[rr * 130 + cc];
        }
    }
}

// ---------------- S partial: S[d][e] += sum_l qT[d][l]*kT[e][l] over l-chunk ----------------
// grid (16 chunks of 256 l, 64 bg); M=N=64, BK=64, wave tile 32x32.
__global__ __launch_bounds__(256, 2) void s_partial_kernel(
    const bf16* __restrict__ qT, const bf16* __restrict__ kT,
    float* __restrict__ S_part) {
    __shared__ __align__(16) bf16 qs[64 * 64];
    __shared__ __align__(16) bf16 ks2[64 * 64];
    const int chunk = blockIdx.x, bg = blockIdx.y;
    const int tid = threadIdx.x, wid = tid >> 6, lane = tid & 63;
    const int r16 = lane & 15, rg = lane >> 4;
    const int wr = wid >> 1, wc = wid & 1;
    const size_t base = ((size_t)bg << 18) + chunk * 256;
    const bf16* qb = qT + base;
    const bf16* kb = kT + base;
    f32x4 acc[2][2] = {};
    for (int ks = 0; ks < 4; ++ks) {
#pragma unroll
        for (int it = 0; it < 2; ++it) {
            int f = (it * 256 + tid) << 4;
            int row = f >> 7;
            int sc = ((f >> 4) & 7) ^ (row & 7);
            gload_lds16((const char*)(qb + ((size_t)row << 12) + ks * 64) + (sc << 4),
                        (char*)qs + ((it * 256 + (wid << 6)) << 4));
            gload_lds16((const char*)(kb + ((size_t)row << 12) + ks * 64) + (sc << 4),
                        (char*)ks2 + ((it * 256 + (wid << 6)) << 4));
        }
        __syncthreads();
#pragma unroll
        for (int kk = 0; kk < 2; ++kk) {
            s16x8 aq[2], bk[2];
#pragma unroll
            for (int mi = 0; mi < 2; ++mi) {
                int row = (wr << 5) + (mi << 4) + r16;
                int off = (row << 7) + ((((kk << 2) + rg) ^ (row & 7)) << 4);
                aq[mi] = *(const s16x8*)((const char*)qs + off);
            }
#pragma unroll
            for (int ni = 0; ni < 2; ++ni) {
                int row = (wc << 5) + (ni << 4) + r16;
                int off = (row << 7) + ((((kk << 2) + rg) ^ (row & 7)) << 4);
                bk[ni] = *(const s16x8*)((const char*)ks2 + off);
            }
#pragma unroll
            for (int mi = 0; mi < 2; ++mi)
#pragma unroll
                for (int ni = 0; ni < 2; ++ni)
                    acc[mi][ni] = mfma16(aq[mi], bk[ni], acc[mi][ni]);
        }
        __syncthreads();
    }
    float* o = S_part + (((size_t)chunk << 6) + bg) * 4096;
#pragma unroll
    for (int mi = 0; mi < 2; ++mi)
#pragma unroll
        for (int ni = 0; ni < 2; ++ni)
#pragma unroll
            for (int r = 0; r < 4; ++r) {
                int row = (wr << 5) + (mi << 4) + (rg << 2) + r;
                int col = (wc << 5) + (ni << 4) + r16;
                o[(row << 6) + col] = acc[mi][ni][r];
            }
}

// ---------------- softmax over e -> attnT[e][d] (transposed for weff's A-operand) ----------------
// grid (4 row-quarters, 64 bg): 16 d-rows/block, 16 lanes/row, 4 e/lane.
__global__ __launch_bounds__(256) void softmax_kernel(const float* __restrict__ S_part,
                                                      bf16* __restrict__ attnT) {
    const int q4 = blockIdx.x, bg = blockIdx.y;
    const int tid = threadIdx.x;
    const int dl = tid >> 4, es = tid & 15;
    const int d = (q4 << 4) + dl;
    const float* base = S_part + ((size_t)bg << 12) + (d << 6) + (es << 2);
    float s[4] = {0.f, 0.f, 0.f, 0.f};
#pragma unroll
    for (int p = 0; p < 16; ++p) {
        f32x4 v4 = *(const f32x4*)(base + ((size_t)p << 18));
        s[0] += v4[0]; s[1] += v4[1]; s[2] += v4[2]; s[3] += v4[3];
    }
    float m = fmaxf(fmaxf(s[0], s[1]), fmaxf(s[2], s[3]));
    m = fmaxf(m, __shfl_xor(m, 1));
    m = fmaxf(m, __shfl_xor(m, 2));
    m = fmaxf(m, __shfl_xor(m, 4));
    m = fmaxf(m, __shfl_xor(m, 8));
    float sum = 0.f;
#pragma unroll
    for (int j = 0; j < 4; ++j) { s[j] = __expf(s[j] - m); sum += s[j]; }
    sum += __shfl_xor(sum, 1);
    sum += __shfl_xor(sum, 2);
    sum += __shfl_xor(sum, 4);
    sum += __shfl_xor(sum, 8);
    float inv = 1.0f / sum;
    bf16* ob = attnT + ((size_t)bg << 12) + d;
#pragma unroll
    for (int j = 0; j < 4; ++j)
        ob[((es << 2) + j) << 6] = __float2bfloat16(s[j] * inv);
}

// ---------------- Weff: WeffT[b][c][64g+e] = sum_d attnT[bg][e][d] * Wproj[64g+d][c] ----------------
// grid (4 c-tiles of 128, 8 b); per g: M=64(e), N=128(c), K=64(d); 4 waves, wave tile 32x64.
__global__ __launch_bounds__(256, 2) void weff_kernel(
    const bf16* __restrict__ attnT, const bf16* __restrict__ Wpt,
    bf16* __restrict__ WeffT) {
    __shared__ __align__(16) bf16 As[64 * 64];    // attnT_g swizzled
    __shared__ __align__(16) bf16 Bs[128 * 64];   // Wpt slice swizzled
    const int c0 = blockIdx.x * 128, b = blockIdx.y;
    const int tid = threadIdx.x, wid = tid >> 6, lane = tid & 63;
    const int r16 = lane & 15, rg = lane >> 4;
    const int wr = wid >> 1, wc = wid & 1;
    bf16* Wout = WeffT + ((size_t)b << 18);
    for (int g = 0; g < 8; ++g) {
        const bf16* at = attnT + ((size_t)(b * 8 + g) << 12);
#pragma unroll
        for (int it = 0; it < 2; ++it) {           // A: 8KB = 512 chunks
            int cidx = it * 256 + tid;
            int row = cidx >> 3, c8 = cidx & 7;
            gload_lds16(at + (row << 6) + ((c8 ^ (row & 7)) << 3),
                        (char*)As + ((it * 256 + (wid << 6)) << 4));
        }
#pragma unroll
        for (int it = 0; it < 4; ++it) {           // B: 16KB = 1024 chunks
            int cidx = it * 256 + tid;
            int row = cidx >> 3, c8 = cidx & 7;
            gload_lds16(Wpt + (size_t)(c0 + row) * 512 + (g << 6) + ((c8 ^ (row & 7)) << 3),
                        (char*)Bs + ((it * 256 + (wid << 6)) << 4));
        }
        __syncthreads();
        f32x4 acc[2][4] = {};
#pragma unroll
        for (int kk = 0; kk < 2; ++kk) {
            s16x8 af[2], bfv[4];
#pragma unroll
            for (int mi = 0; mi < 2; ++mi) {
                int row = (wr << 5) + (mi << 4) + r16;
                int off = (row << 7) + ((((kk << 2) + rg) ^ (row & 7)) << 4);
                af[mi] = *(const s16x8*)((const char*)As + off);
            }
#pragma unroll
            for (int ni = 0; ni < 4; ++ni) {
                int row = (wc << 6) + (ni << 4) + r16;
                int off = (row << 7) + ((((kk << 2) + rg) ^ (row & 7)) << 4);
                bfv[ni] = *(const s16x8*)((const char*)Bs + off);
            }
#pragma unroll
            for (int mi = 0; mi < 2; ++mi)
#pragma unroll
                for (int ni = 0; ni < 4; ++ni)
                    acc[mi][ni] = mfma16(af[mi], bfv[ni], acc[mi][ni]);
        }
        __syncthreads();                            // LDS reads done before next g restages
#pragma unroll
        for (int mi = 0; mi < 2; ++mi)
#pragma unroll
            for (int ni = 0; ni < 4; ++ni) {
                int c = c0 + (wc << 6) + (ni << 4) + r16;
                int e0 = (wr << 5) + (mi << 4) + (rg << 2);
                s16x4 w;
#pragma unroll
                for (int r = 0; r < 4; ++r) w[r] = f2bf_bits(acc[mi][ni][r]);
                *(s16x4*)(Wout + (size_t)c * 512 + (g << 6) + e0) = w;
            }
    }
}

// ---------------- out GEMM: out = V @ WeffT_b^T + b_proj (fp32 out) ----------------
// T1 XCD swizzle (nwg=1024 %8==0). Per-block batch from m0.
__global__ __launch_bounds__(256, 2) void gemm_out_kernel(
    const bf16* __restrict__ A, const bf16* __restrict__ WeffT,
    const float* __restrict__ bias, float* __restrict__ out) {
    __shared__ __align__(16) char smem[32768];
    bf16* As = (bf16*)smem;
    bf16* Bs = (bf16*)(smem + 16384);
    const int tid = threadIdx.x;
    const int wid = tid >> 6, lane = tid & 63;
    const int r16 = lane & 15, rg = lane >> 4;
    const int wr = wid >> 1, wc = wid & 1;
    const int flat = blockIdx.y * 4 + blockIdx.x;        // 1024 tiles
    const int nb = (flat & 7) * 128 + (flat >> 3);
    const int n0 = (nb & 3) * 128;
    const int m0 = (nb >> 2) * 128;
    const bf16* Bt = WeffT + ((size_t)(m0 >> 12) << 18); // per-batch Weff
    f32x4 acc[4][4] = {};
    for (int ks = 0; ks < 8; ++ks) {
        const int k0 = ks * 64;
#pragma unroll
        for (int it = 0; it < 4; ++it) {
            int f = (it * 256 + tid) << 4;
            int row = f >> 7;
            int sc = ((f >> 4) & 7) ^ (row & 7);
            gload_lds16((const char*)(A + (size_t)(m0 + row) * 512 + k0) + (sc << 4),
                        (char*)As + ((it * 256 + (wid << 6)) << 4));
            gload_lds16((const char*)(Bt + (size_t)(n0 + row) * 512 + k0) + (sc << 4),
                        (char*)Bs + ((it * 256 + (wid << 6)) << 4));
        }
        __syncthreads();
#pragma unroll
        for (int kk = 0; kk < 2; ++kk) {
            s16x8 af[4], bfv[4];
#pragma unroll
            for (int mi = 0; mi < 4; ++mi) {
                int row = (wr << 6) + (mi << 4) + r16;
                int off = (row << 7) + ((((kk << 2) + rg) ^ (row & 7)) << 4);
                af[mi] = *(const s16x8*)((const char*)As + off);
            }
#pragma unroll
            for (int ni = 0; ni < 4; ++ni) {
                int row = (wc << 6) + (ni << 4) + r16;
                int off = (row << 7) + ((((kk << 2) + rg) ^ (row & 7)) << 4);
                bfv[ni] = *(const s16x8*)((const char*)Bs + off);
            }
#pragma unroll
            for (int mi = 0; mi < 4; ++mi)
#pragma unroll
                for (int ni = 0; ni < 4; ++ni)
                    acc[mi][ni] = mfma16(af[mi], bfv[ni], acc[mi][ni]);
        }
        __syncthreads();
    }
    float bv[4];
#pragma unroll
    for (int ni = 0; ni < 4; ++ni)
        bv[ni] = bias[n0 + (wc << 6) + (ni << 4) + r16];
#pragma unroll
    for (int mi = 0; mi < 4; ++mi)
#pragma unroll
        for (int ni = 0; ni < 4; ++ni)
#pragma unroll
            for (int r = 0; r < 4; ++r)
                out[(size_t)(m0 + (wr << 6) + (mi << 4) + (rg << 2) + r) * 512 +
                    (n0 + (wc << 6) + (ni << 4) + r16)] = acc[mi][ni][r] + bv[ni];
}

extern "C" void kernel_launch(void* const* d_in, const int* in_sizes, int n_in,
                              void* d_out, int out_size, void* d_ws, size_t ws_size,
                              hipStream_t stream) {
    const float* x      = (const float*)d_in[0];
    const float* W_qkv  = (const float*)d_in[1];
    const float* b_qkv  = (const float*)d_in[2];
    const float* W_proj = (const float*)d_in[3];
    const float* b_proj = (const float*)d_in[4];
    const int*   size_p = (const int*)d_in[5];
    float* out = (float*)d_out;

    char* ws = (char*)d_ws;
    bf16*  Wqkv_t  = (bf16*)ws;                    // 1,572,864
    bf16*  Wproj_t = (bf16*)(ws + 1572864);        //   524,288
    bf16*  qT      = (bf16*)(ws + 2097152);        // 33,554,432
    bf16*  kT      = (bf16*)(ws + 35651584);       // 33,554,432
    bf16*  V       = (bf16*)(ws + 69206016);       // 33,554,432
    float* S_part  = (float*)(ws + 102760448);     // 16,777,216
    bf16*  attnT   = (bf16*)(ws + 119537664);      //    524,288
    bf16*  WeffT   = (bf16*)(ws + 120061952);      // 4,194,304 (ends 124,256,256)

    prep_kernel<<<dim3(64, 16), dim3(256), 0, stream>>>(W_qkv, W_proj, Wqkv_t, Wproj_t,
                                                        size_p, out + (out_size - 1));
    gemm_qkv_kernel<<<dim3(12, 256), dim3(256), 0, stream>>>(x, Wqkv_t, b_qkv, qT, kT, V);
    s_partial_kernel<<<dim3(16, 64), dim3(256), 0, stream>>>(qT, kT, S_part);
    softmax_kernel<<<dim3(4, 64), dim3(256), 0, stream>>>(S_part, attnT);
    weff_kernel<<<dim3(4, 8), dim3(256), 0, stream>>>(attnT, Wproj_t, WeffT);
    gemm_out_kernel<<<dim3(4, 256), dim3(256), 0, stream>>>(V, WeffT, b_proj, out);
    (void)in_sizes; (void)n_in; (void)ws_size;
}

// Round 8
// 254.553 us; speedup vs baseline: 1.0682x; 1.0682x over previous
//
#include <hip/hip_runtime.h>
#include <hip/hip_bf16.h>
#include <stdint.h>

typedef __hip_bfloat16 bf16;
typedef __attribute__((ext_vector_type(8))) short s16x8;   // 8 bf16 (MFMA A/B frag)
typedef __attribute__((ext_vector_type(4))) short s16x4;   // 4 bf16
typedef __attribute__((ext_vector_type(4))) float f32x4;   // MFMA C/D frag

__device__ __forceinline__ short f2bf_bits(float f) {
    union { bf16 b; short s; } u; u.b = __float2bfloat16(f); return u.s;
}

__device__ __forceinline__ void gload_lds16(const void* g, void* l) {
    __builtin_amdgcn_global_load_lds(
        (const __attribute__((address_space(1))) void*)(uintptr_t)g,
        (__attribute__((address_space(3))) void*)(uintptr_t)l,
        16, 0, 0);
}

__device__ __forceinline__ f32x4 mfma16(s16x8 a, s16x8 b, f32x4 c) {
    return __builtin_amdgcn_mfma_f32_16x16x32_bf16(a, b, c, 0, 0, 0);
}

// ---------------- convert x (fp32) -> bf16, vectorized 8/thread ----------------
__global__ __launch_bounds__(256) void cvt_bf16_kernel(const float* __restrict__ in,
                                                       bf16* __restrict__ out, int n8) {
    int i = blockIdx.x * blockDim.x + threadIdx.x;
    int stride = gridDim.x * blockDim.x;
    for (; i < n8; i += stride) {
        f32x4 a = ((const f32x4*)in)[2 * i];
        f32x4 b = ((const f32x4*)in)[2 * i + 1];
        s16x8 o;
        o[0] = f2bf_bits(a[0]); o[1] = f2bf_bits(a[1]);
        o[2] = f2bf_bits(a[2]); o[3] = f2bf_bits(a[3]);
        o[4] = f2bf_bits(b[0]); o[5] = f2bf_bits(b[1]);
        o[6] = f2bf_bits(b[2]); o[7] = f2bf_bits(b[3]);
        ((s16x8*)out)[i] = o;
    }
}

// ---------------- prep: both weight transposes (fp32 -> bf16, out[C][R]=in[R][C]) + tail ----------------
__global__ __launch_bounds__(256) void prep_kernel(const float* __restrict__ Wq,
                                                   const float* __restrict__ Wp,
                                                   bf16* __restrict__ Wqt,
                                                   bf16* __restrict__ Wpt,
                                                   const int* __restrict__ sz,
                                                   float* __restrict__ tailout) {
    if (blockIdx.x == 0 && blockIdx.y == 0 && threadIdx.x == 0)
        tailout[0] = (float)sz[0];
    __shared__ float t[32][33];
    const float* in; bf16* out; int C, c0;
    if (blockIdx.x < 48) { in = Wq; out = Wqt; C = 1536; c0 = blockIdx.x * 32; }
    else                 { in = Wp; out = Wpt; C = 512;  c0 = (blockIdx.x - 48) * 32; }
    int r0 = blockIdx.y * 32;
    int lx = threadIdx.x & 31, ly = threadIdx.x >> 5;
    for (int i = ly; i < 32; i += 8)
        t[i][lx] = in[(size_t)(r0 + i) * C + (c0 + lx)];
    __syncthreads();
    for (int i = ly; i < 32; i += 8)
        out[(size_t)(c0 + i) * 512 + (r0 + lx)] = __float2bfloat16(t[lx][i]);
}

// ---------------- GEMM1: qkv = xb @ Wqkv_t^T + b; writes qT, kT (transposed), V ----------------
// A [32768][512] bf16, Bt [1536][512] bf16, both via global_load_lds (async).
// Tile 128x128, BK=64, 4 waves. T1 XCD swizzle (nwg=3072 %8==0).
__global__ __launch_bounds__(256, 2) void gemm_qkv_kernel(
    const bf16* __restrict__ A, const bf16* __restrict__ Bt,
    const float* __restrict__ bias,
    bf16* __restrict__ qT, bf16* __restrict__ kT, bf16* __restrict__ V) {
    __shared__ __align__(16) char smem[33280];           // max(As+Bs=32KB, tr=128*130*2)
    bf16* As = (bf16*)smem;                              // [128][64] swizzled
    bf16* Bs = (bf16*)(smem + 16384);
    const int tid = threadIdx.x;
    const int wid = tid >> 6, lane = tid & 63;
    const int r16 = lane & 15, rg = lane >> 4;
    const int wr = wid >> 1, wc = wid & 1;
    const int flat = blockIdx.y * 12 + blockIdx.x;       // 3072 tiles
    const int nb = (flat & 7) * 384 + (flat >> 3);
    const int n0 = (nb % 12) * 128;
    const int m0 = (nb / 12) * 128;

    f32x4 acc[4][4] = {};
    for (int ks = 0; ks < 8; ++ks) {
        const int k0 = ks * 64;
#pragma unroll
        for (int it = 0; it < 4; ++it) {
            int f = (it * 256 + tid) << 4;               // byte in 16KB tile
            int row = f >> 7;
            int sc = ((f >> 4) & 7) ^ (row & 7);         // pre-swizzled source chunk
            gload_lds16((const char*)(A + (size_t)(m0 + row) * 512 + k0) + (sc << 4),
                        (char*)As + ((it * 256 + (wid << 6)) << 4));
            gload_lds16((const char*)(Bt + (size_t)(n0 + row) * 512 + k0) + (sc << 4),
                        (char*)Bs + ((it * 256 + (wid << 6)) << 4));
        }
        __syncthreads();
#pragma unroll
        for (int kk = 0; kk < 2; ++kk) {
            s16x8 af[4], bfv[4];
#pragma unroll
            for (int mi = 0; mi < 4; ++mi) {
                int row = (wr << 6) + (mi << 4) + r16;
                int off = (row << 7) + ((((kk << 2) + rg) ^ (row & 7)) << 4);
                af[mi] = *(const s16x8*)((const char*)As + off);
            }
#pragma unroll
            for (int ni = 0; ni < 4; ++ni) {
                int row = (wc << 6) + (ni << 4) + r16;
                int off = (row << 7) + ((((kk << 2) + rg) ^ (row & 7)) << 4);
                bfv[ni] = *(const s16x8*)((const char*)Bs + off);
            }
#pragma unroll
            for (int mi = 0; mi < 4; ++mi)
#pragma unroll
                for (int ni = 0; ni < 4; ++ni)
                    acc[mi][ni] = mfma16(af[mi], bfv[ni], acc[mi][ni]);
        }
        __syncthreads();
    }

    // epilogue: bias, (q) scale, route through LDS [128][130] for layout
    const int bb = m0 >> 12;        // batch
    const int l0 = m0 & 4095;       // l within batch
    const float scale = (n0 < 512) ? 0.015625f : 1.0f;   // L^-0.5 = 1/64 on q
    bf16* tr = (bf16*)smem;
    float bv[4];
#pragma unroll
    for (int ni = 0; ni < 4; ++ni)
        bv[ni] = bias[n0 + (wc << 6) + (ni << 4) + r16];
#pragma unroll
    for (int mi = 0; mi < 4; ++mi)
#pragma unroll
        for (int ni = 0; ni < 4; ++ni) {
            int col = (wc << 6) + (ni << 4) + r16;
#pragma unroll
            for (int r = 0; r < 4; ++r) {
                int row = (wr << 6) + (mi << 4) + (rg << 2) + r;
                tr[row * 130 + col] = __float2bfloat16((acc[mi][ni][r] + bv[ni]) * scale);
            }
        }
    __syncthreads();
    if (n0 < 1024) {                 // q or k block: transposed write qT[b][c][l]
        bf16* dst; int c0;
        if (n0 < 512) { dst = qT; c0 = n0; } else { dst = kT; c0 = n0 - 512; }
#pragma unroll 4
        for (int it = 0; it < 64; ++it) {
            int flat2 = it * 256 + tid;
            int cl = flat2 >> 7, ll = flat2 & 127;
            dst[((size_t)(bb * 512 + c0 + cl) << 12) + (l0 + ll)] = tr[ll * 130 + cl];
        }
    } else {                          // v block: normal layout V[m][c]
        int c0 = n0 - 1024;
#pragma unroll 4
        for (int it = 0; it < 64; ++it) {
            int flat2 = it * 256 + tid;
            int rr = flat2 >> 7, cc = flat2 & 127;
            V[((size_t)(m0 + rr) << 9) + (c0 + cc)] = tr[rr * 130 + cc];
        }
    }
}

// ---------------- S partial: S[d][e] += sum_l qT[d][l]*kT[e][l] over l-chunk ----------------
// grid (16 chunks of 256 l, 64 bg); M=N=64, BK=64, wave tile 32x32.
__global__ __launch_bounds__(256, 2) void s_partial_kernel(
    const bf16* __restrict__ qT, const bf16* __restrict__ kT,
    float* __restrict__ S_part) {
    __shared__ __align__(16) bf16 qs[64 * 64];
    __shared__ __align__(16) bf16 ks2[64 * 64];
    const int chunk = blockIdx.x, bg = blockIdx.y;
    const int tid = threadIdx.x, wid = tid >> 6, lane = tid & 63;
    const int r16 = lane & 15, rg = lane >> 4;
    const int wr = wid >> 1, wc = wid & 1;
    const size_t base = ((size_t)bg << 18) + chunk * 256;
    const bf16* qb = qT + base;
    const bf16* kb = kT + base;
    f32x4 acc[2][2] = {};
    for (int ks = 0; ks < 4; ++ks) {
#pragma unroll
        for (int it = 0; it < 2; ++it) {
            int f = (it * 256 + tid) << 4;
            int row = f >> 7;
            int sc = ((f >> 4) & 7) ^ (row & 7);
            gload_lds16((const char*)(qb + ((size_t)row << 12) + ks * 64) + (sc << 4),
                        (char*)qs + ((it * 256 + (wid << 6)) << 4));
            gload_lds16((const char*)(kb + ((size_t)row << 12) + ks * 64) + (sc << 4),
                        (char*)ks2 + ((it * 256 + (wid << 6)) << 4));
        }
        __syncthreads();
#pragma unroll
        for (int kk = 0; kk < 2; ++kk) {
            s16x8 aq[2], bk[2];
#pragma unroll
            for (int mi = 0; mi < 2; ++mi) {
                int row = (wr << 5) + (mi << 4) + r16;
                int off = (row << 7) + ((((kk << 2) + rg) ^ (row & 7)) << 4);
                aq[mi] = *(const s16x8*)((const char*)qs + off);
            }
#pragma unroll
            for (int ni = 0; ni < 2; ++ni) {
                int row = (wc << 5) + (ni << 4) + r16;
                int off = (row << 7) + ((((kk << 2) + rg) ^ (row & 7)) << 4);
                bk[ni] = *(const s16x8*)((const char*)ks2 + off);
            }
#pragma unroll
            for (int mi = 0; mi < 2; ++mi)
#pragma unroll
                for (int ni = 0; ni < 2; ++ni)
                    acc[mi][ni] = mfma16(aq[mi], bk[ni], acc[mi][ni]);
        }
        __syncthreads();
    }
    float* o = S_part + (((size_t)chunk << 6) + bg) * 4096;
#pragma unroll
    for (int mi = 0; mi < 2; ++mi)
#pragma unroll
        for (int ni = 0; ni < 2; ++ni)
#pragma unroll
            for (int r = 0; r < 4; ++r) {
                int row = (wr << 5) + (mi << 4) + (rg << 2) + r;
                int col = (wc << 5) + (ni << 4) + r16;
                o[(row << 6) + col] = acc[mi][ni][r];
            }
}

// ---------------- softmax over e -> attnT[e][d] (transposed for weff's A-operand) ----------------
// grid (4 row-quarters, 64 bg): 16 d-rows/block, 16 lanes/row, 4 e/lane.
__global__ __launch_bounds__(256) void softmax_kernel(const float* __restrict__ S_part,
                                                      bf16* __restrict__ attnT) {
    const int q4 = blockIdx.x, bg = blockIdx.y;
    const int tid = threadIdx.x;
    const int dl = tid >> 4, es = tid & 15;
    const int d = (q4 << 4) + dl;
    const float* base = S_part + ((size_t)bg << 12) + (d << 6) + (es << 2);
    float s[4] = {0.f, 0.f, 0.f, 0.f};
#pragma unroll
    for (int p = 0; p < 16; ++p) {
        f32x4 v4 = *(const f32x4*)(base + ((size_t)p << 18));
        s[0] += v4[0]; s[1] += v4[1]; s[2] += v4[2]; s[3] += v4[3];
    }
    float m = fmaxf(fmaxf(s[0], s[1]), fmaxf(s[2], s[3]));
    m = fmaxf(m, __shfl_xor(m, 1));
    m = fmaxf(m, __shfl_xor(m, 2));
    m = fmaxf(m, __shfl_xor(m, 4));
    m = fmaxf(m, __shfl_xor(m, 8));
    float sum = 0.f;
#pragma unroll
    for (int j = 0; j < 4; ++j) { s[j] = __expf(s[j] - m); sum += s[j]; }
    sum += __shfl_xor(sum, 1);
    sum += __shfl_xor(sum, 2);
    sum += __shfl_xor(sum, 4);
    sum += __shfl_xor(sum, 8);
    float inv = 1.0f / sum;
    bf16* ob = attnT + ((size_t)bg << 12) + d;
#pragma unroll
    for (int j = 0; j < 4; ++j)
        ob[((es << 2) + j) << 6] = __float2bfloat16(s[j] * inv);
}

// ---------------- Weff: WeffT[b][c][64g+e] = sum_d attnT[bg][e][d] * Wproj[64g+d][c] ----------------
// grid (4 c-tiles of 128, 8 b); per g: M=64(e), N=128(c), K=64(d); 4 waves, wave tile 32x64.
__global__ __launch_bounds__(256, 2) void weff_kernel(
    const bf16* __restrict__ attnT, const bf16* __restrict__ Wpt,
    bf16* __restrict__ WeffT) {
    __shared__ __align__(16) bf16 As[64 * 64];    // attnT_g swizzled
    __shared__ __align__(16) bf16 Bs[128 * 64];   // Wpt slice swizzled
    const int c0 = blockIdx.x * 128, b = blockIdx.y;
    const int tid = threadIdx.x, wid = tid >> 6, lane = tid & 63;
    const int r16 = lane & 15, rg = lane >> 4;
    const int wr = wid >> 1, wc = wid & 1;
    bf16* Wout = WeffT + ((size_t)b << 18);
    for (int g = 0; g < 8; ++g) {
        const bf16* at = attnT + ((size_t)(b * 8 + g) << 12);
#pragma unroll
        for (int it = 0; it < 2; ++it) {           // A: 8KB = 512 chunks
            int cidx = it * 256 + tid;
            int row = cidx >> 3, c8 = cidx & 7;
            gload_lds16(at + (row << 6) + ((c8 ^ (row & 7)) << 3),
                        (char*)As + ((it * 256 + (wid << 6)) << 4));
        }
#pragma unroll
        for (int it = 0; it < 4; ++it) {           // B: 16KB = 1024 chunks
            int cidx = it * 256 + tid;
            int row = cidx >> 3, c8 = cidx & 7;
            gload_lds16(Wpt + (size_t)(c0 + row) * 512 + (g << 6) + ((c8 ^ (row & 7)) << 3),
                        (char*)Bs + ((it * 256 + (wid << 6)) << 4));
        }
        __syncthreads();
        f32x4 acc[2][4] = {};
#pragma unroll
        for (int kk = 0; kk < 2; ++kk) {
            s16x8 af[2], bfv[4];
#pragma unroll
            for (int mi = 0; mi < 2; ++mi) {
                int row = (wr << 5) + (mi << 4) + r16;
                int off = (row << 7) + ((((kk << 2) + rg) ^ (row & 7)) << 4);
                af[mi] = *(const s16x8*)((const char*)As + off);
            }
#pragma unroll
            for (int ni = 0; ni < 4; ++ni) {
                int row = (wc << 6) + (ni << 4) + r16;
                int off = (row << 7) + ((((kk << 2) + rg) ^ (row & 7)) << 4);
                bfv[ni] = *(const s16x8*)((const char*)Bs + off);
            }
#pragma unroll
            for (int mi = 0; mi < 2; ++mi)
#pragma unroll
                for (int ni = 0; ni < 4; ++ni)
                    acc[mi][ni] = mfma16(af[mi], bfv[ni], acc[mi][ni]);
        }
        __syncthreads();                            // LDS reads done before next g restages
#pragma unroll
        for (int mi = 0; mi < 2; ++mi)
#pragma unroll
            for (int ni = 0; ni < 4; ++ni) {
                int c = c0 + (wc << 6) + (ni << 4) + r16;
                int e0 = (wr << 5) + (mi << 4) + (rg << 2);
                s16x4 w;
#pragma unroll
                for (int r = 0; r < 4; ++r) w[r] = f2bf_bits(acc[mi][ni][r]);
                *(s16x4*)(Wout + (size_t)c * 512 + (g << 6) + e0) = w;
            }
    }
}

// ---------------- out GEMM: out = V @ WeffT_b^T + b_proj (fp32 out) ----------------
// T1 XCD swizzle (nwg=1024 %8==0). Per-block batch from m0.
__global__ __launch_bounds__(256, 2) void gemm_out_kernel(
    const bf16* __restrict__ A, const bf16* __restrict__ WeffT,
    const float* __restrict__ bias, float* __restrict__ out) {
    __shared__ __align__(16) char smem[32768];
    bf16* As = (bf16*)smem;
    bf16* Bs = (bf16*)(smem + 16384);
    const int tid = threadIdx.x;
    const int wid = tid >> 6, lane = tid & 63;
    const int r16 = lane & 15, rg = lane >> 4;
    const int wr = wid >> 1, wc = wid & 1;
    const int flat = blockIdx.y * 4 + blockIdx.x;        // 1024 tiles
    const int nb = (flat & 7) * 128 + (flat >> 3);
    const int n0 = (nb & 3) * 128;
    const int m0 = (nb >> 2) * 128;
    const bf16* Bt = WeffT + ((size_t)(m0 >> 12) << 18); // per-batch Weff
    f32x4 acc[4][4] = {};
    for (int ks = 0; ks < 8; ++ks) {
        const int k0 = ks * 64;
#pragma unroll
        for (int it = 0; it < 4; ++it) {
            int f = (it * 256 + tid) << 4;
            int row = f >> 7;
            int sc = ((f >> 4) & 7) ^ (row & 7);
            gload_lds16((const char*)(A + (size_t)(m0 + row) * 512 + k0) + (sc << 4),
                        (char*)As + ((it * 256 + (wid << 6)) << 4));
            gload_lds16((const char*)(Bt + (size_t)(n0 + row) * 512 + k0) + (sc << 4),
                        (char*)Bs + ((it * 256 + (wid << 6)) << 4));
        }
        __syncthreads();
#pragma unroll
        for (int kk = 0; kk < 2; ++kk) {
            s16x8 af[4], bfv[4];
#pragma unroll
            for (int mi = 0; mi < 4; ++mi) {
                int row = (wr << 6) + (mi << 4) + r16;
                int off = (row << 7) + ((((kk << 2) + rg) ^ (row & 7)) << 4);
                af[mi] = *(const s16x8*)((const char*)As + off);
            }
#pragma unroll
            for (int ni = 0; ni < 4; ++ni) {
                int row = (wc << 6) + (ni << 4) + r16;
                int off = (row << 7) + ((((kk << 2) + rg) ^ (row & 7)) << 4);
                bfv[ni] = *(const s16x8*)((const char*)Bs + off);
            }
#pragma unroll
            for (int mi = 0; mi < 4; ++mi)
#pragma unroll
                for (int ni = 0; ni < 4; ++ni)
                    acc[mi][ni] = mfma16(af[mi], bfv[ni], acc[mi][ni]);
        }
        __syncthreads();
    }
    float bv[4];
#pragma unroll
    for (int ni = 0; ni < 4; ++ni)
        bv[ni] = bias[n0 + (wc << 6) + (ni << 4) + r16];
#pragma unroll
    for (int mi = 0; mi < 4; ++mi)
#pragma unroll
        for (int ni = 0; ni < 4; ++ni)
#pragma unroll
            for (int r = 0; r < 4; ++r)
                out[(size_t)(m0 + (wr << 6) + (mi << 4) + (rg << 2) + r) * 512 +
                    (n0 + (wc << 6) + (ni << 4) + r16)] = acc[mi][ni][r] + bv[ni];
}

extern "C" void kernel_launch(void* const* d_in, const int* in_sizes, int n_in,
                              void* d_out, int out_size, void* d_ws, size_t ws_size,
                              hipStream_t stream) {
    const float* x      = (const float*)d_in[0];
    const float* W_qkv  = (const float*)d_in[1];
    const float* b_qkv  = (const float*)d_in[2];
    const float* W_proj = (const float*)d_in[3];
    const float* b_proj = (const float*)d_in[4];
    const int*   size_p = (const int*)d_in[5];
    float* out = (float*)d_out;

    char* ws = (char*)d_ws;
    bf16*  xb      = (bf16*)ws;                    // 33,554,432 B
    bf16*  Wqkv_t  = (bf16*)(ws + 33554432);       //  1,572,864
    bf16*  Wproj_t = (bf16*)(ws + 35127296);       //    524,288
    bf16*  qT      = (bf16*)(ws + 35651584);       // 33,554,432
    bf16*  kT      = (bf16*)(ws + 69206016);       // 33,554,432
    bf16*  V       = (bf16*)(ws + 102760448);      // 33,554,432 (ends 136,314,880)
    // aliases into dead xb region (xb dead after gemm_qkv):
    float* S_part  = (float*)xb;                   // 16,777,216
    bf16*  attnT   = (bf16*)(ws + 16777216);       //    524,288
    bf16*  WeffT   = (bf16*)(ws + 17301504);       //  4,194,304 (ends 21,495,808 < 33.5MB)

    cvt_bf16_kernel<<<dim3(2048), dim3(256), 0, stream>>>(x, xb, 2097152);
    prep_kernel<<<dim3(64, 16), dim3(256), 0, stream>>>(W_qkv, W_proj, Wqkv_t, Wproj_t,
                                                        size_p, out + (out_size - 1));
    gemm_qkv_kernel<<<dim3(12, 256), dim3(256), 0, stream>>>(xb, Wqkv_t, b_qkv, qT, kT, V);
    s_partial_kernel<<<dim3(16, 64), dim3(256), 0, stream>>>(qT, kT, S_part);
    softmax_kernel<<<dim3(4, 64), dim3(256), 0, stream>>>(S_part, attnT);
    weff_kernel<<<dim3(4, 8), dim3(256), 0, stream>>>(attnT, Wproj_t, WeffT);
    gemm_out_kernel<<<dim3(4, 256), dim3(256), 0, stream>>>(V, WeffT, b_proj, out);
    (void)in_sizes; (void)n_in; (void)ws_size;
}